// Round 1
// baseline (174.513 us; speedup 1.0000x reference)
//
#include <hip/hip_runtime.h>

#define RMAX 60
#define KTAPS 121          // 2*RMAX+1
#define WP 144             // padded weight row (floats) = 36 float4
#define PADL 7             // zero pad on the left of the weight row
#define NC 3
#define NH 256
#define NW 256

__device__ __forceinline__ int refl(int q) {
    // jnp.pad mode='reflect' (no edge repeat); valid for q in (-NH, 2*NH-1)
    if (q < 0) q = -q;
    if (q > NH - 1) q = 2 * (NH - 1) - q;
    return q;
}

// One block (64 threads = 1 wave) per sample: build normalized, zero-padded kernel row.
__global__ void wgen(const int* __restrict__ steps, const float* __restrict__ sigmas,
                     float* __restrict__ wpad) {
    const int b = blockIdx.x;
    const int t = threadIdx.x;               // 0..63
    const float sg = sigmas[steps[b]];
    const float r = ceilf(3.0f * sg);
    const float inv2s2 = 0.5f / (sg * sg);
    const float o0 = (float)(t - RMAX);
    float w0 = (fabsf(o0) <= r) ? expf(-o0 * o0 * inv2s2) : 0.0f;
    const int t1 = t + 64;
    float w1 = 0.0f;
    if (t1 < KTAPS) {
        const float o1 = (float)(t1 - RMAX);
        w1 = (fabsf(o1) <= r) ? expf(-o1 * o1 * inv2s2) : 0.0f;
    }
    float s = w0 + w1;
#pragma unroll
    for (int off = 32; off > 0; off >>= 1) s += __shfl_down(s, off);
    const float inv = 1.0f / __shfl(s, 0);
    float* row = wpad + b * WP;
    if (t < PADL) row[t] = 0.0f;                       // [0,7)
    row[PADL + t] = w0 * inv;                          // [7,71)
    row[PADL + t1] = (t1 < KTAPS) ? w1 * inv : 0.0f;   // [71,135)
    if (t < WP - (PADL + 128)) row[PADL + 128 + t] = 0.0f; // [135,144)
}

// Horizontal pass: block = 4 waves = 4 rows; lane owns 4 consecutive x (float4).
__global__ __launch_bounds__(256) void hpass(const float* __restrict__ in,
                                             const float* __restrict__ wpad,
                                             const int* __restrict__ steps,
                                             const float* __restrict__ sigmas,
                                             float* __restrict__ tmp) {
    __shared__ __align__(16) float wl[WP];
    const int b = blockIdx.z, c = blockIdx.y;
    const int t = threadIdx.x;
    if (t < WP / 4) ((float4*)wl)[t] = ((const float4*)(wpad + b * WP))[t];
    __syncthreads();
    const int wave = t >> 6, lane = t & 63;
    const int y = blockIdx.x * 4 + wave;
    const float* __restrict__ row = in + ((b * NC + c) * NH + y) * NW;
    const float sg = sigmas[steps[b]];
    const int r = (int)ceilf(3.0f * sg);
    const int rp = (r + 3) & ~3;            // radius rounded to mult of 4 (zero-weight taps)
    const int x0 = lane * 4;
    float4 acc = make_float4(0.f, 0.f, 0.f, 0.f);
    const int M = (rp >> 1) + 1;            // chunks of 4 input pixels
    for (int m = 0; m < M; ++m) {
        const int p = x0 - rp + 4 * m;
        float4 v;
        if (p >= 0 && p <= NW - 4) {
            v = *(const float4*)(row + p);
        } else {
            v.x = row[refl(p)]; v.y = row[refl(p + 1)];
            v.z = row[refl(p + 2)]; v.w = row[refl(p + 3)];
        }
        const int q0 = 64 - rp + 4 * m;     // aligned: rp%4==0
        const float4 wa = *(const float4*)&wl[q0];
        const float4 wb = *(const float4*)&wl[q0 + 4];
        // out j gets w[q0 + 3 + k - j] for input element k
        acc.x = fmaf(v.x, wa.w, acc.x); acc.x = fmaf(v.y, wb.x, acc.x);
        acc.x = fmaf(v.z, wb.y, acc.x); acc.x = fmaf(v.w, wb.z, acc.x);
        acc.y = fmaf(v.x, wa.z, acc.y); acc.y = fmaf(v.y, wa.w, acc.y);
        acc.y = fmaf(v.z, wb.x, acc.y); acc.y = fmaf(v.w, wb.y, acc.y);
        acc.z = fmaf(v.x, wa.y, acc.z); acc.z = fmaf(v.y, wa.z, acc.z);
        acc.z = fmaf(v.z, wa.w, acc.z); acc.z = fmaf(v.w, wb.x, acc.z);
        acc.w = fmaf(v.x, wa.x, acc.w); acc.w = fmaf(v.y, wa.y, acc.w);
        acc.w = fmaf(v.z, wa.z, acc.w); acc.w = fmaf(v.w, wa.w, acc.w);
    }
    *(float4*)(tmp + ((b * NC + c) * NH + y) * NW + x0) = acc;
}

// Vertical pass: block = 4 waves; each wave owns an 8-row tile x full width.
// Lane owns 4 x (float4). Each loaded row-float4 feeds all 8 accumulators.
__global__ __launch_bounds__(256) void vpass(const float* __restrict__ tmp,
                                             const float* __restrict__ wpad,
                                             const int* __restrict__ steps,
                                             const float* __restrict__ sigmas,
                                             float* __restrict__ out) {
    __shared__ __align__(16) float wl[WP];
    const int b = blockIdx.z, c = blockIdx.y;
    const int t = threadIdx.x;
    if (t < WP / 4) ((float4*)wl)[t] = ((const float4*)(wpad + b * WP))[t];
    __syncthreads();
    const int wave = t >> 6, lane = t & 63;
    const int yt = blockIdx.x * 32 + wave * 8;
    const int x0 = lane * 4;
    const float* __restrict__ plane = tmp + (b * NC + c) * NH * NW;
    const float sg = sigmas[steps[b]];
    const int r = (int)ceilf(3.0f * sg);
    const int rp = (r + 3) & ~3;
    float4 acc[8];
#pragma unroll
    for (int j = 0; j < 8; ++j) acc[j] = make_float4(0.f, 0.f, 0.f, 0.f);
    for (int i0 = yt - rp; i0 <= yt + 7 + rp; i0 += 8) {
        const int s0 = i0 - yt + 60;        // aligned mult-of-4 (rp%4==0), in [0,127]
        float wv[16];
        *(float4*)&wv[0]  = *(const float4*)&wl[s0];
        *(float4*)&wv[4]  = *(const float4*)&wl[s0 + 4];
        *(float4*)&wv[8]  = *(const float4*)&wl[s0 + 8];
        *(float4*)&wv[12] = *(const float4*)&wl[s0 + 12];
#pragma unroll
        for (int di = 0; di < 8; ++di) {
            const int ir = refl(i0 + di);
            const float4 v = *(const float4*)(plane + ir * NW + x0);
#pragma unroll
            for (int j = 0; j < 8; ++j) {
                const float w = wv[7 + di - j];
                acc[j].x = fmaf(v.x, w, acc[j].x);
                acc[j].y = fmaf(v.y, w, acc[j].y);
                acc[j].z = fmaf(v.z, w, acc[j].z);
                acc[j].w = fmaf(v.w, w, acc[j].w);
            }
        }
    }
#pragma unroll
    for (int j = 0; j < 8; ++j)
        *(float4*)(out + ((b * NC + c) * NH + yt + j) * NW + x0) = acc[j];
}

extern "C" void kernel_launch(void* const* d_in, const int* in_sizes, int n_in,
                              void* d_out, int out_size, void* d_ws, size_t ws_size,
                              hipStream_t stream) {
    const float* x      = (const float*)d_in[0];
    const int*   steps  = (const int*)d_in[1];
    const float* sigmas = (const float*)d_in[2];
    float* out = (float*)d_out;
    const int B = in_sizes[1];              // 64

    float* wpad = (float*)d_ws;                                   // B*WP floats
    float* tmp  = (float*)((char*)d_ws + (size_t)B * WP * 4);     // B*C*H*W floats

    wgen<<<dim3(B), dim3(64), 0, stream>>>(steps, sigmas, wpad);
    hpass<<<dim3(NH / 4, NC, B), dim3(256), 0, stream>>>(x, wpad, steps, sigmas, tmp);
    vpass<<<dim3(NH / 32, NC, B), dim3(256), 0, stream>>>(tmp, wpad, steps, sigmas, out);
}

// Round 2
// 98.784 us; speedup vs baseline: 1.7666x; 1.7666x over previous
//
#include <hip/hip_runtime.h>

#define RMAX 60
#define KTAPS 121          // 2*RMAX+1
#define WP 144             // padded weight row (floats) = 36 float4
#define PADL 7             // zero pad on the left of the weight row
#define NC 3
#define NH 256
#define NW 256

__device__ __forceinline__ int refl(int q) {
    // jnp.pad mode='reflect'; valid for q in (-NH, 2*NH-1). Branch-free.
    q = q < 0 ? -q : q;
    int d = (NH - 1) - q;
    d = d < 0 ? -d : d;
    return (NH - 1) - d;
}

// One block (64 threads = 1 wave) per sample: normalized, zero-padded kernel row.
__global__ void wgen(const int* __restrict__ steps, const float* __restrict__ sigmas,
                     float* __restrict__ wpad) {
    const int b = blockIdx.x;
    const int t = threadIdx.x;               // 0..63
    const float sg = sigmas[steps[b]];
    const float r = ceilf(3.0f * sg);
    const float inv2s2 = 0.5f / (sg * sg);
    const float o0 = (float)(t - RMAX);
    float w0 = (fabsf(o0) <= r) ? expf(-o0 * o0 * inv2s2) : 0.0f;
    const int t1 = t + 64;
    float w1 = 0.0f;
    if (t1 < KTAPS) {
        const float o1 = (float)(t1 - RMAX);
        w1 = (fabsf(o1) <= r) ? expf(-o1 * o1 * inv2s2) : 0.0f;
    }
    float s = w0 + w1;
#pragma unroll
    for (int off = 32; off > 0; off >>= 1) s += __shfl_down(s, off);
    const float inv = 1.0f / __shfl(s, 0);
    float* row = wpad + b * WP;
    if (t < PADL) row[t] = 0.0f;                       // [0,7)
    row[PADL + t] = w0 * inv;                          // [7,71)
    row[PADL + t1] = (t1 < KTAPS) ? w1 * inv : 0.0f;   // [71,135)
    if (t < WP - (PADL + 128)) row[PADL + 128 + t] = 0.0f; // [135,144)
}

// ---------------- horizontal conv body (templated unroll) ----------------
template<int RPS>
__device__ __forceinline__ void hconv(int rpd, const float (* __restrict__ sr)[384],
                                      const float* __restrict__ wl, int x0,
                                      float4 acc[4]) {
    const int RP = (RPS > 0) ? RPS : rpd;
#define HSTEP(mm) do {                                                        \
    const int q0 = 64 - RP + 4 * (mm);                                        \
    const float4 wa = *(const float4*)&wl[q0];                                \
    const float4 wb = *(const float4*)&wl[q0 + 4];                            \
    _Pragma("unroll")                                                         \
    for (int rr = 0; rr < 4; ++rr) {                                          \
        const float4 v = *(const float4*)&sr[rr][q0 - 4 + x0];                \
        acc[rr].x = fmaf(v.x, wa.w, acc[rr].x);                               \
        acc[rr].x = fmaf(v.y, wb.x, acc[rr].x);                               \
        acc[rr].x = fmaf(v.z, wb.y, acc[rr].x);                               \
        acc[rr].x = fmaf(v.w, wb.z, acc[rr].x);                               \
        acc[rr].y = fmaf(v.x, wa.z, acc[rr].y);                               \
        acc[rr].y = fmaf(v.y, wa.w, acc[rr].y);                               \
        acc[rr].y = fmaf(v.z, wb.x, acc[rr].y);                               \
        acc[rr].y = fmaf(v.w, wb.y, acc[rr].y);                               \
        acc[rr].z = fmaf(v.x, wa.y, acc[rr].z);                               \
        acc[rr].z = fmaf(v.y, wa.z, acc[rr].z);                               \
        acc[rr].z = fmaf(v.z, wa.w, acc[rr].z);                               \
        acc[rr].z = fmaf(v.w, wb.x, acc[rr].z);                               \
        acc[rr].w = fmaf(v.x, wa.x, acc[rr].w);                               \
        acc[rr].w = fmaf(v.y, wa.y, acc[rr].w);                               \
        acc[rr].w = fmaf(v.z, wa.z, acc[rr].w);                               \
        acc[rr].w = fmaf(v.w, wa.w, acc[rr].w);                               \
    }                                                                         \
} while (0)
    if constexpr (RPS > 0) {
        constexpr int M = RPS / 2 + 1;
#pragma unroll
        for (int m = 0; m < M; ++m) { HSTEP(m); }
    } else {
        const int M = RP / 2 + 1;
        for (int m = 0; m < M; ++m) { HSTEP(m); }
    }
#undef HSTEP
}

// Horizontal pass: block = 4 waves; each wave stages 4 reflect-padded rows in
// wave-private LDS, then runs a fully-unrolled sliding-window conv from LDS.
__global__ __launch_bounds__(256) void hpass(const float* __restrict__ in,
                                             const float* __restrict__ wpad,
                                             const int* __restrict__ steps,
                                             const float* __restrict__ sigmas,
                                             float* __restrict__ tmp) {
    __shared__ __align__(16) float wl[WP];
    __shared__ __align__(16) float srow[16][384];
    const int b = blockIdx.z, c = blockIdx.y;
    const int t = threadIdx.x;
    const int wave = t >> 6, lane = t & 63;
    if (t < WP / 4) ((float4*)wl)[t] = ((const float4*)(wpad + b * WP))[t];
    const int ybase = blockIdx.x * 16 + wave * 4;
    const float* __restrict__ plane = in + (size_t)(b * NC + c) * NH * NW;
    float (* __restrict__ sr)[384] = &srow[wave * 4];
    const int x0 = lane * 4;
    // stage 4 rows: main body (coalesced float4) + reflect halos (60 each side)
#pragma unroll
    for (int rr = 0; rr < 4; ++rr) {
        const float* __restrict__ row = plane + (size_t)(ybase + rr) * NW;
        *(float4*)&sr[rr][60 + x0] = *(const float4*)(row + x0);
        if (lane < 60) {
            sr[rr][lane]       = row[60 - lane];    // p = lane-60 < 0 -> refl
            sr[rr][316 + lane] = row[254 - lane];   // p = 256+lane   -> refl
        }
    }
    __syncthreads();    // wl is block-shared; srow is wave-private
    const float sg = sigmas[steps[b]];
    const int rp = ((int)ceilf(3.0f * sg) + 3) & ~3;
    float4 acc[4];
#pragma unroll
    for (int rr = 0; rr < 4; ++rr) acc[rr] = make_float4(0.f, 0.f, 0.f, 0.f);
    switch (rp) {
        case 4:  hconv<4>(rp, sr, wl, x0, acc); break;
        case 8:  hconv<8>(rp, sr, wl, x0, acc); break;
        case 12: hconv<12>(rp, sr, wl, x0, acc); break;
        case 16: hconv<16>(rp, sr, wl, x0, acc); break;
        case 20: hconv<20>(rp, sr, wl, x0, acc); break;
        case 24: hconv<24>(rp, sr, wl, x0, acc); break;
        case 28: hconv<28>(rp, sr, wl, x0, acc); break;
        case 36: hconv<36>(rp, sr, wl, x0, acc); break;
        case 44: hconv<44>(rp, sr, wl, x0, acc); break;
        case 52: hconv<52>(rp, sr, wl, x0, acc); break;
        case 60: hconv<60>(rp, sr, wl, x0, acc); break;
        default: hconv<-1>(rp, sr, wl, x0, acc); break;
    }
    float* __restrict__ outp = tmp + (size_t)(b * NC + c) * NH * NW;
#pragma unroll
    for (int rr = 0; rr < 4; ++rr)
        *(float4*)(outp + (size_t)(ybase + rr) * NW + x0) = acc[rr];
}

// ---------------- vertical conv body (templated unroll) ----------------
template<int RPS>
__device__ __forceinline__ void vconv(int rpd, const float* __restrict__ plane,
                                      const float* __restrict__ wl, int yt, int x0,
                                      float4 acc[8]) {
    const int RP = (RPS > 0) ? RPS : rpd;
#define VSTEP(itt) do {                                                       \
    const int i0 = yt - RP + 8 * (itt);                                       \
    const int s0 = 60 - RP + 8 * (itt);                                       \
    float wv[16];                                                             \
    _Pragma("unroll")                                                         \
    for (int k = 0; k < 4; ++k)                                               \
        *(float4*)&wv[4 * k] = *(const float4*)&wl[s0 + 4 * k];               \
    _Pragma("unroll")                                                         \
    for (int di = 0; di < 8; ++di) {                                          \
        const int ir = refl(i0 + di);                                         \
        const float4 v = *(const float4*)(plane + (size_t)ir * NW + x0);      \
        _Pragma("unroll")                                                     \
        for (int j = 0; j < 8; ++j) {                                         \
            const float w = wv[7 + di - j];                                   \
            acc[j].x = fmaf(v.x, w, acc[j].x);                                \
            acc[j].y = fmaf(v.y, w, acc[j].y);                                \
            acc[j].z = fmaf(v.z, w, acc[j].z);                                \
            acc[j].w = fmaf(v.w, w, acc[j].w);                                \
        }                                                                     \
    }                                                                         \
} while (0)
    if constexpr (RPS > 0) {
        constexpr int NI = RPS / 4 + 1;
#pragma unroll
        for (int it = 0; it < NI; ++it) { VSTEP(it); }
    } else {
        const int NI = RP / 4 + 1;
        for (int it = 0; it < NI; ++it) { VSTEP(it); }
    }
#undef VSTEP
}

// Vertical pass: block = 4 waves; each wave owns an 8-row tile x full width.
__global__ __launch_bounds__(256) void vpass(const float* __restrict__ tmp,
                                             const float* __restrict__ wpad,
                                             const int* __restrict__ steps,
                                             const float* __restrict__ sigmas,
                                             float* __restrict__ out) {
    __shared__ __align__(16) float wl[WP];
    const int b = blockIdx.z, c = blockIdx.y;
    const int t = threadIdx.x;
    if (t < WP / 4) ((float4*)wl)[t] = ((const float4*)(wpad + b * WP))[t];
    __syncthreads();
    const int wave = t >> 6, lane = t & 63;
    const int yt = blockIdx.x * 32 + wave * 8;
    const int x0 = lane * 4;
    const float* __restrict__ plane = tmp + (size_t)(b * NC + c) * NH * NW;
    const float sg = sigmas[steps[b]];
    const int rp = ((int)ceilf(3.0f * sg) + 3) & ~3;
    float4 acc[8];
#pragma unroll
    for (int j = 0; j < 8; ++j) acc[j] = make_float4(0.f, 0.f, 0.f, 0.f);
    switch (rp) {
        case 4:  vconv<4>(rp, plane, wl, yt, x0, acc); break;
        case 8:  vconv<8>(rp, plane, wl, yt, x0, acc); break;
        case 12: vconv<12>(rp, plane, wl, yt, x0, acc); break;
        case 16: vconv<16>(rp, plane, wl, yt, x0, acc); break;
        case 20: vconv<20>(rp, plane, wl, yt, x0, acc); break;
        case 24: vconv<24>(rp, plane, wl, yt, x0, acc); break;
        case 28: vconv<28>(rp, plane, wl, yt, x0, acc); break;
        case 36: vconv<36>(rp, plane, wl, yt, x0, acc); break;
        case 44: vconv<44>(rp, plane, wl, yt, x0, acc); break;
        case 52: vconv<52>(rp, plane, wl, yt, x0, acc); break;
        case 60: vconv<60>(rp, plane, wl, yt, x0, acc); break;
        default: vconv<-1>(rp, plane, wl, yt, x0, acc); break;
    }
    float* __restrict__ outp = out + (size_t)(b * NC + c) * NH * NW;
#pragma unroll
    for (int j = 0; j < 8; ++j)
        *(float4*)(outp + (size_t)(yt + j) * NW + x0) = acc[j];
}

extern "C" void kernel_launch(void* const* d_in, const int* in_sizes, int n_in,
                              void* d_out, int out_size, void* d_ws, size_t ws_size,
                              hipStream_t stream) {
    const float* x      = (const float*)d_in[0];
    const int*   steps  = (const int*)d_in[1];
    const float* sigmas = (const float*)d_in[2];
    float* out = (float*)d_out;
    const int B = in_sizes[1];              // 64

    float* wpad = (float*)d_ws;                                   // B*WP floats
    float* tmp  = (float*)((char*)d_ws + (size_t)B * WP * 4);     // B*C*H*W floats

    wgen<<<dim3(B), dim3(64), 0, stream>>>(steps, sigmas, wpad);
    hpass<<<dim3(NH / 16, NC, B), dim3(256), 0, stream>>>(x, wpad, steps, sigmas, tmp);
    vpass<<<dim3(NH / 32, NC, B), dim3(256), 0, stream>>>(tmp, wpad, steps, sigmas, out);
}

// Round 3
// 96.319 us; speedup vs baseline: 1.8118x; 1.0256x over previous
//
#include <hip/hip_runtime.h>

#define RMAX 60
#define KTAPS 121          // 2*RMAX+1
#define WP 144             // padded weight row (floats) = 36 float4
#define PADL 7             // zero pad on the left of the weight row
#define NC 3
#define NH 256
#define NW 256

__device__ __forceinline__ int refl(int q) {
    // jnp.pad mode='reflect'; valid for q in (-NH, 2*NH-1). Branch-free.
    q = q < 0 ? -q : q;
    int d = (NH - 1) - q;
    d = d < 0 ? -d : d;
    return (NH - 1) - d;
}

// One block (64 threads = 1 wave) per sample: normalized, zero-padded kernel row.
__global__ void wgen(const int* __restrict__ steps, const float* __restrict__ sigmas,
                     float* __restrict__ wpad) {
    const int b = blockIdx.x;
    const int t = threadIdx.x;               // 0..63
    const float sg = sigmas[steps[b]];
    const float r = ceilf(3.0f * sg);
    const float inv2s2 = 0.5f / (sg * sg);
    const float o0 = (float)(t - RMAX);
    float w0 = (fabsf(o0) <= r) ? expf(-o0 * o0 * inv2s2) : 0.0f;
    const int t1 = t + 64;
    float w1 = 0.0f;
    if (t1 < KTAPS) {
        const float o1 = (float)(t1 - RMAX);
        w1 = (fabsf(o1) <= r) ? expf(-o1 * o1 * inv2s2) : 0.0f;
    }
    float s = w0 + w1;
#pragma unroll
    for (int off = 32; off > 0; off >>= 1) s += __shfl_down(s, off);
    const float inv = 1.0f / __shfl(s, 0);
    float* row = wpad + b * WP;
    if (t < PADL) row[t] = 0.0f;                       // [0,7)
    row[PADL + t] = w0 * inv;                          // [7,71)
    row[PADL + t1] = (t1 < KTAPS) ? w1 * inv : 0.0f;   // [71,135)
    if (t < WP - (PADL + 128)) row[PADL + 128 + t] = 0.0f; // [135,144)
}

// Horizontal pass: block = 4 waves; each wave stages 4 reflect-padded rows in
// wave-private LDS, then runs a sliding-window conv from LDS.
// Runtime M loop (peel 1 + unroll 2; M is always odd) -> ~1KB code shared by
// all samples (no per-radius switch -> no i-cache thrash).
__global__ __launch_bounds__(256) void hpass(const float* __restrict__ in,
                                             const float* __restrict__ wpad,
                                             const int* __restrict__ steps,
                                             const float* __restrict__ sigmas,
                                             float* __restrict__ tmp) {
    __shared__ __align__(16) float wl[WP];
    __shared__ __align__(16) float srow[16][384];
    const int b = blockIdx.x, c = blockIdx.y;          // b fastest-varying: balance
    const int t = threadIdx.x;
    const int wave = t >> 6, lane = t & 63;
    if (t < WP / 4) ((float4*)wl)[t] = ((const float4*)(wpad + b * WP))[t];
    const int ybase = blockIdx.z * 16 + wave * 4;
    const float* __restrict__ plane = in + (size_t)(b * NC + c) * NH * NW;
    float (* __restrict__ sr)[384] = &srow[wave * 4];
    const int x0 = lane * 4;
    // stage 4 rows: main body (coalesced float4) + reflect halos (60 each side)
#pragma unroll
    for (int rr = 0; rr < 4; ++rr) {
        const float* __restrict__ row = plane + (size_t)(ybase + rr) * NW;
        *(float4*)&sr[rr][60 + x0] = *(const float4*)(row + x0);
        if (lane < 60) {
            sr[rr][lane]       = row[60 - lane];    // p = lane-60 < 0 -> refl
            sr[rr][316 + lane] = row[254 - lane];   // p = 256+lane   -> refl
        }
    }
    __syncthreads();
    const float sg = sigmas[steps[b]];
    const int rp = ((int)ceilf(3.0f * sg) + 3) & ~3;
    float4 acc[4];
#pragma unroll
    for (int rr = 0; rr < 4; ++rr) acc[rr] = make_float4(0.f, 0.f, 0.f, 0.f);

#define HSTEP(q0) do {                                                        \
    const float4 wa = *(const float4*)&wl[(q0)];                              \
    const float4 wb = *(const float4*)&wl[(q0) + 4];                          \
    _Pragma("unroll")                                                         \
    for (int rr = 0; rr < 4; ++rr) {                                          \
        const float4 v = *(const float4*)&sr[rr][(q0) - 4 + x0];              \
        acc[rr].x = fmaf(v.x, wa.w, acc[rr].x);                               \
        acc[rr].x = fmaf(v.y, wb.x, acc[rr].x);                               \
        acc[rr].x = fmaf(v.z, wb.y, acc[rr].x);                               \
        acc[rr].x = fmaf(v.w, wb.z, acc[rr].x);                               \
        acc[rr].y = fmaf(v.x, wa.z, acc[rr].y);                               \
        acc[rr].y = fmaf(v.y, wa.w, acc[rr].y);                               \
        acc[rr].y = fmaf(v.z, wb.x, acc[rr].y);                               \
        acc[rr].y = fmaf(v.w, wb.y, acc[rr].y);                               \
        acc[rr].z = fmaf(v.x, wa.y, acc[rr].z);                               \
        acc[rr].z = fmaf(v.y, wa.z, acc[rr].z);                               \
        acc[rr].z = fmaf(v.z, wa.w, acc[rr].z);                               \
        acc[rr].z = fmaf(v.w, wb.x, acc[rr].z);                               \
        acc[rr].w = fmaf(v.x, wa.x, acc[rr].w);                               \
        acc[rr].w = fmaf(v.y, wa.y, acc[rr].w);                               \
        acc[rr].w = fmaf(v.z, wa.z, acc[rr].w);                               \
        acc[rr].w = fmaf(v.w, wa.w, acc[rr].w);                               \
    }                                                                         \
} while (0)

    // q0 walks 64-rp .. 64+rp step 4;  M = rp/2+1 steps (always odd)
    const int qend = 64 + rp;
    int q0 = 64 - rp;
    HSTEP(q0);
    q0 += 4;
    for (; q0 <= qend; q0 += 8) {
        HSTEP(q0);
        HSTEP(q0 + 4);
    }
#undef HSTEP

    float* __restrict__ outp = tmp + (size_t)(b * NC + c) * NH * NW;
#pragma unroll
    for (int rr = 0; rr < 4; ++rr)
        *(float4*)(outp + (size_t)(ybase + rr) * NW + x0) = acc[rr];
}

// Vertical pass: block = 4 waves; each wave owns an 8-row tile x full width.
// Lane owns 4 x (float4); each loaded row-float4 feeds all 8 accumulators.
// Runtime NI loop, body = 8 loads + 256 FMAs (~1.3KB code, i-cache resident).
__global__ __launch_bounds__(256) void vpass(const float* __restrict__ tmp,
                                             const float* __restrict__ wpad,
                                             const int* __restrict__ steps,
                                             const float* __restrict__ sigmas,
                                             float* __restrict__ out) {
    __shared__ __align__(16) float wl[WP];
    const int b = blockIdx.x, c = blockIdx.y;          // b fastest-varying
    const int t = threadIdx.x;
    if (t < WP / 4) ((float4*)wl)[t] = ((const float4*)(wpad + b * WP))[t];
    __syncthreads();
    const int wave = t >> 6, lane = t & 63;
    const int yt = blockIdx.z * 32 + wave * 8;
    const int x0 = lane * 4;
    const float* __restrict__ plane = tmp + (size_t)(b * NC + c) * NH * NW;
    const float sg = sigmas[steps[b]];
    const int rp = ((int)ceilf(3.0f * sg) + 3) & ~3;
    float4 acc[8];
#pragma unroll
    for (int j = 0; j < 8; ++j) acc[j] = make_float4(0.f, 0.f, 0.f, 0.f);

    const int NI = rp / 4 + 1;                 // chunks of 8 rows
    for (int it = 0; it < NI; ++it) {
        const int i0 = yt - rp + 8 * it;
        const int s0 = 60 - rp + 8 * it;       // mult of 4: aligned float4 reads
        float wv[16];
#pragma unroll
        for (int k = 0; k < 4; ++k)
            *(float4*)&wv[4 * k] = *(const float4*)&wl[s0 + 4 * k];
#pragma unroll
        for (int di = 0; di < 8; ++di) {
            const int ir = refl(i0 + di);
            const float4 v = *(const float4*)(plane + (size_t)ir * NW + x0);
#pragma unroll
            for (int j = 0; j < 8; ++j) {
                const float w = wv[7 + di - j];
                acc[j].x = fmaf(v.x, w, acc[j].x);
                acc[j].y = fmaf(v.y, w, acc[j].y);
                acc[j].z = fmaf(v.z, w, acc[j].z);
                acc[j].w = fmaf(v.w, w, acc[j].w);
            }
        }
    }

    float* __restrict__ outp = out + (size_t)(b * NC + c) * NH * NW;
#pragma unroll
    for (int j = 0; j < 8; ++j)
        *(float4*)(outp + (size_t)(yt + j) * NW + x0) = acc[j];
}

extern "C" void kernel_launch(void* const* d_in, const int* in_sizes, int n_in,
                              void* d_out, int out_size, void* d_ws, size_t ws_size,
                              hipStream_t stream) {
    const float* x      = (const float*)d_in[0];
    const int*   steps  = (const int*)d_in[1];
    const float* sigmas = (const float*)d_in[2];
    float* out = (float*)d_out;
    const int B = in_sizes[1];              // 64

    float* wpad = (float*)d_ws;                                   // B*WP floats
    float* tmp  = (float*)((char*)d_ws + (size_t)B * WP * 4);     // B*C*H*W floats

    wgen<<<dim3(B), dim3(64), 0, stream>>>(steps, sigmas, wpad);
    hpass<<<dim3(B, NC, NH / 16), dim3(256), 0, stream>>>(x, wpad, steps, sigmas, tmp);
    vpass<<<dim3(B, NC, NH / 32), dim3(256), 0, stream>>>(tmp, wpad, steps, sigmas, out);
}

// Round 4
// 91.772 us; speedup vs baseline: 1.9016x; 1.0495x over previous
//
#include <hip/hip_runtime.h>

#define RMAX 60
#define KTAPS 121          // 2*RMAX+1
#define WP 144             // padded weight row (floats) = 36 float4
#define PADL 7             // zero pad on the left of the weight row
#define NC 3
#define NH 256
#define NW 256

__device__ __forceinline__ int refl(int q) {
    // jnp.pad mode='reflect'; valid for q in (-NH, 2*NH-1). Branch-free.
    q = q < 0 ? -q : q;
    int d = (NH - 1) - q;
    d = d < 0 ? -d : d;
    return (NH - 1) - d;
}

// One block (64 threads = 1 wave) per sample: normalized, zero-padded kernel row.
__global__ void wgen(const int* __restrict__ steps, const float* __restrict__ sigmas,
                     float* __restrict__ wpad) {
    const int b = blockIdx.x;
    const int t = threadIdx.x;               // 0..63
    const float sg = sigmas[steps[b]];
    const float r = ceilf(3.0f * sg);
    const float inv2s2 = 0.5f / (sg * sg);
    const float o0 = (float)(t - RMAX);
    float w0 = (fabsf(o0) <= r) ? expf(-o0 * o0 * inv2s2) : 0.0f;
    const int t1 = t + 64;
    float w1 = 0.0f;
    if (t1 < KTAPS) {
        const float o1 = (float)(t1 - RMAX);
        w1 = (fabsf(o1) <= r) ? expf(-o1 * o1 * inv2s2) : 0.0f;
    }
    float s = w0 + w1;
#pragma unroll
    for (int off = 32; off > 0; off >>= 1) s += __shfl_down(s, off);
    const float inv = 1.0f / __shfl(s, 0);
    float* row = wpad + b * WP;
    if (t < PADL) row[t] = 0.0f;                       // [0,7)
    row[PADL + t] = w0 * inv;                          // [7,71)
    row[PADL + t1] = (t1 < KTAPS) ? w1 * inv : 0.0f;   // [71,135)
    if (t < WP - (PADL + 128)) row[PADL + 128 + t] = 0.0f; // [135,144)
}

// Horizontal pass, work-balanced: each WAVE owns a chain of 4-row tiles;
// chain length tph ~ 1/M so per-wave work is uniform across sigmas.
// 64 tiles of 4 rows per (b,c) plane; wave fw handles tiles [fw*tph,(fw+1)*tph).
__global__ __launch_bounds__(256) void hpass(const float* __restrict__ in,
                                             const float* __restrict__ wpad,
                                             const int* __restrict__ steps,
                                             const float* __restrict__ sigmas,
                                             float* __restrict__ tmp) {
    __shared__ __align__(16) float wl[WP];
    __shared__ __align__(16) float srow[4][4][384];    // [wave][row][x]
    const int b = blockIdx.x, c = blockIdx.y;          // b fastest: heavy spread
    const int t = threadIdx.x;
    const int wave = t >> 6, lane = t & 63;
    if (t < WP / 4) ((float4*)wl)[t] = ((const float4*)(wpad + b * WP))[t];
    __syncthreads();                                   // wl ready; no syncs after

    const float sg = sigmas[steps[b]];
    const int rp = ((int)ceilf(3.0f * sg) + 3) & ~3;
    const int M = rp / 2 + 1;                          // HSTEPs per tile (odd)
    const int tph = max(1, 32 / (M + 3));              // tiles per wave
    const int fw = blockIdx.z * 4 + wave;              // flat wave id [0,64)
    const int tile0 = fw * tph;
    if (tile0 >= 64) return;
    const int tile1 = min(tile0 + tph, 64);

    const float* __restrict__ plane = in + (size_t)(b * NC + c) * NH * NW;
    float* __restrict__ outp = tmp + (size_t)(b * NC + c) * NH * NW;
    float (* __restrict__ sr)[384] = srow[wave];
    const int x0 = lane * 4;

    for (int tile = tile0; tile < tile1; ++tile) {
        const int ybase = tile * 4;
        // stage 4 reflect-padded rows (wave-private LDS, in-wave RAW only)
#pragma unroll
        for (int rr = 0; rr < 4; ++rr) {
            const float* __restrict__ row = plane + (size_t)(ybase + rr) * NW;
            *(float4*)&sr[rr][60 + x0] = *(const float4*)(row + x0);
            if (lane < 60) {
                sr[rr][lane]       = row[60 - lane];    // left reflect halo
                sr[rr][316 + lane] = row[254 - lane];   // right reflect halo
            }
        }
        float4 acc[4];
#pragma unroll
        for (int rr = 0; rr < 4; ++rr) acc[rr] = make_float4(0.f, 0.f, 0.f, 0.f);

#define HSTEP(q0) do {                                                        \
    const float4 wa = *(const float4*)&wl[(q0)];                              \
    const float4 wb = *(const float4*)&wl[(q0) + 4];                          \
    _Pragma("unroll")                                                         \
    for (int rr = 0; rr < 4; ++rr) {                                          \
        const float4 v = *(const float4*)&sr[rr][(q0) - 4 + x0];              \
        acc[rr].x = fmaf(v.x, wa.w, acc[rr].x);                               \
        acc[rr].x = fmaf(v.y, wb.x, acc[rr].x);                               \
        acc[rr].x = fmaf(v.z, wb.y, acc[rr].x);                               \
        acc[rr].x = fmaf(v.w, wb.z, acc[rr].x);                               \
        acc[rr].y = fmaf(v.x, wa.z, acc[rr].y);                               \
        acc[rr].y = fmaf(v.y, wa.w, acc[rr].y);                               \
        acc[rr].y = fmaf(v.z, wb.x, acc[rr].y);                               \
        acc[rr].y = fmaf(v.w, wb.y, acc[rr].y);                               \
        acc[rr].z = fmaf(v.x, wa.y, acc[rr].z);                               \
        acc[rr].z = fmaf(v.y, wa.z, acc[rr].z);                               \
        acc[rr].z = fmaf(v.z, wa.w, acc[rr].z);                               \
        acc[rr].z = fmaf(v.w, wb.x, acc[rr].z);                               \
        acc[rr].w = fmaf(v.x, wa.x, acc[rr].w);                               \
        acc[rr].w = fmaf(v.y, wa.y, acc[rr].w);                               \
        acc[rr].w = fmaf(v.z, wa.z, acc[rr].w);                               \
        acc[rr].w = fmaf(v.w, wa.w, acc[rr].w);                               \
    }                                                                         \
} while (0)
        // q0 walks 64-rp .. 64+rp step 4; M steps (always odd): peel 1, unroll 2
        const int qend = 64 + rp;
        int q0 = 64 - rp;
        HSTEP(q0);
        q0 += 4;
        for (; q0 <= qend; q0 += 8) {
            HSTEP(q0);
            HSTEP(q0 + 4);
        }
#undef HSTEP
#pragma unroll
        for (int rr = 0; rr < 4; ++rr)
            *(float4*)(outp + (size_t)(ybase + rr) * NW + x0) = acc[rr];
    }
}

// Vertical pass, work-balanced: each WAVE owns a chain of 8-row tiles;
// chain length tpb ~ 1/NI. 32 tiles of 8 rows per plane.
__global__ __launch_bounds__(256) void vpass(const float* __restrict__ tmp,
                                             const float* __restrict__ wpad,
                                             const int* __restrict__ steps,
                                             const float* __restrict__ sigmas,
                                             float* __restrict__ out) {
    __shared__ __align__(16) float wl[WP];
    const int b = blockIdx.x, c = blockIdx.y;
    const int t = threadIdx.x;
    if (t < WP / 4) ((float4*)wl)[t] = ((const float4*)(wpad + b * WP))[t];
    __syncthreads();

    const float sg = sigmas[steps[b]];
    const int rp = ((int)ceilf(3.0f * sg) + 3) & ~3;
    const int NI = rp / 4 + 1;                         // 8-row chunks per tile
    const int tpb = max(1, 16 / NI);                   // tiles per wave
    const int wave = t >> 6, lane = t & 63;
    const int fw = blockIdx.z * 4 + wave;              // flat wave id [0,32)
    const int tile0 = fw * tpb;
    if (tile0 >= 32) return;
    const int tile1 = min(tile0 + tpb, 32);

    const int x0 = lane * 4;
    const float* __restrict__ plane = tmp + (size_t)(b * NC + c) * NH * NW;
    float* __restrict__ outp = out + (size_t)(b * NC + c) * NH * NW;

    for (int tile = tile0; tile < tile1; ++tile) {
        const int yt = tile * 8;
        float4 acc[8];
#pragma unroll
        for (int j = 0; j < 8; ++j) acc[j] = make_float4(0.f, 0.f, 0.f, 0.f);

        for (int it = 0; it < NI; ++it) {
            const int i0 = yt - rp + 8 * it;
            const int s0 = 60 - rp + 8 * it;           // mult of 4: aligned reads
            float wv[16];
#pragma unroll
            for (int k = 0; k < 4; ++k)
                *(float4*)&wv[4 * k] = *(const float4*)&wl[s0 + 4 * k];
#pragma unroll
            for (int di = 0; di < 8; ++di) {
                const int ir = refl(i0 + di);
                const float4 v = *(const float4*)(plane + (size_t)ir * NW + x0);
#pragma unroll
                for (int j = 0; j < 8; ++j) {
                    const float w = wv[7 + di - j];
                    acc[j].x = fmaf(v.x, w, acc[j].x);
                    acc[j].y = fmaf(v.y, w, acc[j].y);
                    acc[j].z = fmaf(v.z, w, acc[j].z);
                    acc[j].w = fmaf(v.w, w, acc[j].w);
                }
            }
        }
#pragma unroll
        for (int j = 0; j < 8; ++j)
            *(float4*)(outp + (size_t)(yt + j) * NW + x0) = acc[j];
    }
}

extern "C" void kernel_launch(void* const* d_in, const int* in_sizes, int n_in,
                              void* d_out, int out_size, void* d_ws, size_t ws_size,
                              hipStream_t stream) {
    const float* x      = (const float*)d_in[0];
    const int*   steps  = (const int*)d_in[1];
    const float* sigmas = (const float*)d_in[2];
    float* out = (float*)d_out;
    const int B = in_sizes[1];              // 64

    float* wpad = (float*)d_ws;                                   // B*WP floats
    float* tmp  = (float*)((char*)d_ws + (size_t)B * WP * 4);     // B*C*H*W floats

    wgen<<<dim3(B), dim3(64), 0, stream>>>(steps, sigmas, wpad);
    hpass<<<dim3(B, NC, 16), dim3(256), 0, stream>>>(x, wpad, steps, sigmas, tmp);
    vpass<<<dim3(B, NC, 8), dim3(256), 0, stream>>>(tmp, wpad, steps, sigmas, out);
}

// Round 5
// 75.247 us; speedup vs baseline: 2.3192x; 1.2196x over previous
//
#include <hip/hip_runtime.h>

#define RMAX 60
#define KTAPS 121          // 2*RMAX+1
#define WPH 144            // hpass weight row: taps at [67+t], zeros outside
#define WPV 160            // vpass weight row: taps at [76+t], zeros outside
#define NC 3
#define NH 256
#define NW 256
#define NPLANE (64 * NC)   // 192
#define HPB 16             // hpass blocks per plane (16 blocks x 4 waves = 64 tiles)
#define VPB 4              // vpass blocks per plane (4 blocks x 4 waves = 16 tiles)

__device__ __forceinline__ int refl(int q) {
    // jnp.pad mode='reflect'; valid for q in (-NH, 2*NH-1). Branch-free.
    q = q < 0 ? -q : q;
    int d = (NH - 1) - q;
    d = d < 0 ? -d : d;
    return (NH - 1) - d;
}

// One block (1 wave) per sample: normalized kernel in two padded layouts.
__global__ void wgen(const int* __restrict__ steps, const float* __restrict__ sigmas,
                     float* __restrict__ wpadH, float* __restrict__ wpadV) {
    const int b = blockIdx.x;
    const int t = threadIdx.x;               // 0..63
    const float sg = sigmas[steps[b]];
    const float r = ceilf(3.0f * sg);
    const float inv2s2 = 0.5f / (sg * sg);
    const float o0 = (float)(t - RMAX);                  // tap t-60
    float w0 = (fabsf(o0) <= r) ? expf(-o0 * o0 * inv2s2) : 0.0f;
    const float o1 = (float)(t + 4);                     // tap t+4
    const int t1 = t + 64;
    float w1 = (t1 < KTAPS && fabsf(o1) <= r) ? expf(-o1 * o1 * inv2s2) : 0.0f;
    float s = w0 + w1;
#pragma unroll
    for (int off = 32; off > 0; off >>= 1) s += __shfl_down(s, off);
    const float inv = 1.0f / __shfl(s, 0);
    // H layout (center 67, same as verified rounds 1-4)
    float* rh = wpadH + b * WPH;
    if (t < 7) rh[t] = 0.0f;                           // [0,7)
    rh[7 + t] = w0 * inv;                              // [7,71)
    rh[7 + t1] = (t1 < KTAPS) ? w1 * inv : 0.0f;       // [71,135)
    if (t < 8) rh[136 + t] = 0.0f;                     // [136,144)
    // V layout (center 76, 16B-aligned window reads)
    float* rv = wpadV + b * WPV;
    if (t < 16) rv[t] = 0.0f;                          // [0,16)
    rv[16 + t] = w0 * inv;                             // [16,80)
    rv[80 + t] = (t1 < KTAPS) ? w1 * inv : 0.0f;       // [80,144)
    if (t < 16) rv[144 + t] = 0.0f;                    // [144,160)
}

// Horizontal pass: one 4-row tile per WAVE, flat item space, no early exits.
// 192 planes x 16 blocks; all 4 waves of a block share the plane/weights.
__global__ __launch_bounds__(256) void hpass(const float* __restrict__ in,
                                             const float* __restrict__ wpadH,
                                             const int* __restrict__ steps,
                                             const float* __restrict__ sigmas,
                                             float* __restrict__ tmp) {
    __shared__ __align__(16) float wl[WPH];
    __shared__ __align__(16) float srow[4][4][384];    // [wave][row][x]
    // chunked XCD swizzle (bijective: nwg = 3072, divisible by 8)
    const int nwg = NPLANE * HPB;
    const int pb = blockIdx.x;
    const int lbid = (pb & 7) * (nwg >> 3) + (pb >> 3);
    const int plane = lbid / HPB;                      // 0..191
    const int b = plane / NC, c = plane % NC;
    const int t = threadIdx.x;
    const int wave = t >> 6, lane = t & 63;
    if (t < WPH / 4) ((float4*)wl)[t] = ((const float4*)(wpadH + b * WPH))[t];
    __syncthreads();

    const float sg = sigmas[steps[b]];
    const int rp = ((int)ceilf(3.0f * sg) + 3) & ~3;
    const int tile = (lbid % HPB) * 4 + wave;          // 0..63
    const int ybase = tile * 4;

    const float* __restrict__ plptr = in + (size_t)plane * NH * NW;
    float* __restrict__ outp = tmp + (size_t)plane * NH * NW;
    float (* __restrict__ sr)[384] = srow[wave];
    const int x0 = lane * 4;

    // stage 4 reflect-padded rows (wave-private LDS)
#pragma unroll
    for (int rr = 0; rr < 4; ++rr) {
        const float* __restrict__ row = plptr + (size_t)(ybase + rr) * NW;
        *(float4*)&sr[rr][60 + x0] = *(const float4*)(row + x0);
        if (lane < 60) {
            sr[rr][lane]       = row[60 - lane];    // left reflect halo
            sr[rr][316 + lane] = row[254 - lane];   // right reflect halo
        }
    }
    float4 acc[4];
#pragma unroll
    for (int rr = 0; rr < 4; ++rr) acc[rr] = make_float4(0.f, 0.f, 0.f, 0.f);

#define HSTEP(q0) do {                                                        \
    const float4 wa = *(const float4*)&wl[(q0)];                              \
    const float4 wb = *(const float4*)&wl[(q0) + 4];                          \
    _Pragma("unroll")                                                         \
    for (int rr = 0; rr < 4; ++rr) {                                          \
        const float4 v = *(const float4*)&sr[rr][(q0) - 4 + x0];              \
        acc[rr].x = fmaf(v.x, wa.w, acc[rr].x);                               \
        acc[rr].x = fmaf(v.y, wb.x, acc[rr].x);                               \
        acc[rr].x = fmaf(v.z, wb.y, acc[rr].x);                               \
        acc[rr].x = fmaf(v.w, wb.z, acc[rr].x);                               \
        acc[rr].y = fmaf(v.x, wa.z, acc[rr].y);                               \
        acc[rr].y = fmaf(v.y, wa.w, acc[rr].y);                               \
        acc[rr].y = fmaf(v.z, wb.x, acc[rr].y);                               \
        acc[rr].y = fmaf(v.w, wb.y, acc[rr].y);                               \
        acc[rr].z = fmaf(v.x, wa.y, acc[rr].z);                               \
        acc[rr].z = fmaf(v.y, wa.z, acc[rr].z);                               \
        acc[rr].z = fmaf(v.z, wa.w, acc[rr].z);                               \
        acc[rr].z = fmaf(v.w, wb.x, acc[rr].z);                               \
        acc[rr].w = fmaf(v.x, wa.x, acc[rr].w);                               \
        acc[rr].w = fmaf(v.y, wa.y, acc[rr].w);                               \
        acc[rr].w = fmaf(v.z, wa.z, acc[rr].w);                               \
        acc[rr].w = fmaf(v.w, wa.w, acc[rr].w);                               \
    }                                                                         \
} while (0)
    // q0 walks 64-rp .. 64+rp step 4; M steps (always odd): peel 1, unroll 2
    const int qend = 64 + rp;
    int q0 = 64 - rp;
    HSTEP(q0);
    q0 += 4;
    for (; q0 <= qend; q0 += 8) {
        HSTEP(q0);
        HSTEP(q0 + 4);
    }
#undef HSTEP
#pragma unroll
    for (int rr = 0; rr < 4; ++rr)
        *(float4*)(outp + (size_t)(ybase + rr) * NW + x0) = acc[rr];
}

// Vertical pass: one 16-row tile per WAVE (16 float4 accumulators).
// Each loaded input row feeds all 16 accs -> read amplification (16+2rp)/16.
__global__ __launch_bounds__(256) void vpass(const float* __restrict__ tmp,
                                             const float* __restrict__ wpadV,
                                             const int* __restrict__ steps,
                                             const float* __restrict__ sigmas,
                                             float* __restrict__ out) {
    __shared__ __align__(16) float wl[WPV];
    const int nwg = NPLANE * VPB;                      // 768
    const int pb = blockIdx.x;
    const int lbid = (pb & 7) * (nwg >> 3) + (pb >> 3);
    const int plane = lbid / VPB;
    const int b = plane / NC, c = plane % NC;
    const int t = threadIdx.x;
    if (t < WPV / 4) ((float4*)wl)[t] = ((const float4*)(wpadV + b * WPV))[t];
    __syncthreads();

    const float sg = sigmas[steps[b]];
    const int rp = ((int)ceilf(3.0f * sg) + 3) & ~3;
    const int NI = 2 + rp / 4;                         // 8-row chunks
    const int wave = t >> 6, lane = t & 63;
    const int tile = (lbid % VPB) * 4 + wave;          // 0..15
    const int yt = tile * 16;
    const int x0 = lane * 4;
    const float* __restrict__ plptr = tmp + (size_t)plane * NH * NW;
    float* __restrict__ outp = out + (size_t)plane * NH * NW;

    float4 acc[16];
#pragma unroll
    for (int j = 0; j < 16; ++j) acc[j] = make_float4(0.f, 0.f, 0.f, 0.f);

    for (int it = 0; it < NI; ++it) {
        const int i0 = yt - rp + 8 * it;               // first input row of chunk
        const int s0 = 72 - rp + 8 * it;               // >=12, mult of 4
        float wv[24];                                  // wv[k] = wl[s0-12+k]
#pragma unroll
        for (int k = 0; k < 6; ++k)
            *(float4*)&wv[4 * k] = *(const float4*)&wl[s0 - 12 + 4 * k];
#pragma unroll
        for (int di = 0; di < 8; ++di) {
            const int ir = refl(i0 + di);
            const float4 v = *(const float4*)(plptr + (size_t)ir * NW + x0);
#pragma unroll
            for (int j = 0; j < 16; ++j) {
                const float w = wv[16 + di - j];       // tap (i0+di)-(yt+j)
                acc[j].x = fmaf(v.x, w, acc[j].x);
                acc[j].y = fmaf(v.y, w, acc[j].y);
                acc[j].z = fmaf(v.z, w, acc[j].z);
                acc[j].w = fmaf(v.w, w, acc[j].w);
            }
        }
    }
#pragma unroll
    for (int j = 0; j < 16; ++j)
        *(float4*)(outp + (size_t)(yt + j) * NW + x0) = acc[j];
}

extern "C" void kernel_launch(void* const* d_in, const int* in_sizes, int n_in,
                              void* d_out, int out_size, void* d_ws, size_t ws_size,
                              hipStream_t stream) {
    const float* x      = (const float*)d_in[0];
    const int*   steps  = (const int*)d_in[1];
    const float* sigmas = (const float*)d_in[2];
    float* out = (float*)d_out;
    const int B = in_sizes[1];              // 64

    float* wpadH = (float*)d_ws;                                    // B*WPH floats
    float* wpadV = wpadH + (size_t)B * WPH;                         // B*WPV floats
    float* tmp   = wpadV + (size_t)B * WPV;                         // B*C*H*W floats

    wgen<<<dim3(B), dim3(64), 0, stream>>>(steps, sigmas, wpadH, wpadV);
    hpass<<<dim3(NPLANE * HPB), dim3(256), 0, stream>>>(x, wpadH, steps, sigmas, tmp);
    vpass<<<dim3(NPLANE * VPB), dim3(256), 0, stream>>>(tmp, wpadV, steps, sigmas, out);
}

// Round 6
// 73.169 us; speedup vs baseline: 2.3851x; 1.0284x over previous
//
#include <hip/hip_runtime.h>

#define RMAX 60
#define KTAPS 121          // 2*RMAX+1
#define WPH 144            // hpass weight row: taps at [67+t], zeros outside
#define WPV 160            // vpass weight row: taps at [76+t], zeros outside
#define NC 3
#define NH 256
#define NW 256
#define NPLANE (64 * NC)   // 192
#define HPB 16             // hpass blocks per plane (16 blocks x 4 waves = 64 tiles)
#define VPB 4              // vpass blocks per plane (4 blocks x 4 waves = 16 tiles)

__device__ __forceinline__ int refl(int q) {
    // jnp.pad mode='reflect'; valid for q in (-NH, 2*NH-1). Branch-free.
    q = q < 0 ? -q : q;
    int d = (NH - 1) - q;
    d = d < 0 ? -d : d;
    return (NH - 1) - d;
}

// One block (1 wave) per sample: normalized kernel in two padded layouts.
__global__ void wgen(const int* __restrict__ steps, const float* __restrict__ sigmas,
                     float* __restrict__ wpadH, float* __restrict__ wpadV) {
    const int b = blockIdx.x;
    const int t = threadIdx.x;               // 0..63
    const float sg = sigmas[steps[b]];
    const float r = ceilf(3.0f * sg);
    const float inv2s2 = 0.5f / (sg * sg);
    const float o0 = (float)(t - RMAX);                  // tap t-60
    float w0 = (fabsf(o0) <= r) ? expf(-o0 * o0 * inv2s2) : 0.0f;
    const float o1 = (float)(t + 4);                     // tap t+4
    const int t1 = t + 64;
    float w1 = (t1 < KTAPS && fabsf(o1) <= r) ? expf(-o1 * o1 * inv2s2) : 0.0f;
    float s = w0 + w1;
#pragma unroll
    for (int off = 32; off > 0; off >>= 1) s += __shfl_down(s, off);
    const float inv = 1.0f / __shfl(s, 0);
    // H layout (center 67)
    float* rh = wpadH + b * WPH;
    if (t < 7) rh[t] = 0.0f;                           // [0,7)
    rh[7 + t] = w0 * inv;                              // [7,71)
    rh[7 + t1] = (t1 < KTAPS) ? w1 * inv : 0.0f;       // [71,135)
    if (t < 8) rh[136 + t] = 0.0f;                     // [136,144)
    // V layout (center 76, 16B-aligned window reads)
    float* rv = wpadV + b * WPV;
    if (t < 16) rv[t] = 0.0f;                          // [0,16)
    rv[16 + t] = w0 * inv;                             // [16,80)
    rv[80 + t] = (t1 < KTAPS) ? w1 * inv : 0.0f;       // [80,144)
    if (t < 16) rv[144 + t] = 0.0f;                    // [144,160)
}

// Horizontal pass: one 4-row tile per WAVE, flat item space, no early exits.
// __launch_bounds__(256,2): VGPR cap ~256 so the unrolled body stays in VGPRs
// (at the default cap of 68 the compiler spilled acc/inputs to AGPRs).
__global__ __launch_bounds__(256, 2) void hpass(const float* __restrict__ in,
                                                const float* __restrict__ wpadH,
                                                const int* __restrict__ steps,
                                                const float* __restrict__ sigmas,
                                                float* __restrict__ tmp) {
    __shared__ __align__(16) float wl[WPH];
    __shared__ __align__(16) float srow[4][4][384];    // [wave][row][x]
    // chunked XCD swizzle (bijective: nwg = 3072, divisible by 8)
    const int nwg = NPLANE * HPB;
    const int pb = blockIdx.x;
    const int lbid = (pb & 7) * (nwg >> 3) + (pb >> 3);
    const int plane = lbid / HPB;                      // 0..191
    const int b = plane / NC;
    const int t = threadIdx.x;
    const int wave = t >> 6, lane = t & 63;
    if (t < WPH / 4) ((float4*)wl)[t] = ((const float4*)(wpadH + b * WPH))[t];
    __syncthreads();

    const float sg = sigmas[steps[b]];
    const int rp = ((int)ceilf(3.0f * sg) + 3) & ~3;
    const int tile = (lbid % HPB) * 4 + wave;          // 0..63
    const int ybase = tile * 4;

    const float* __restrict__ plptr = in + (size_t)plane * NH * NW;
    float* __restrict__ outp = tmp + (size_t)plane * NH * NW;
    float (* __restrict__ sr)[384] = srow[wave];
    const int x0 = lane * 4;

    // stage 4 reflect-padded rows (wave-private LDS)
#pragma unroll
    for (int rr = 0; rr < 4; ++rr) {
        const float* __restrict__ row = plptr + (size_t)(ybase + rr) * NW;
        *(float4*)&sr[rr][60 + x0] = *(const float4*)(row + x0);
        if (lane < 60) {
            sr[rr][lane]       = row[60 - lane];    // left reflect halo
            sr[rr][316 + lane] = row[254 - lane];   // right reflect halo
        }
    }
    float4 acc[4];
#pragma unroll
    for (int rr = 0; rr < 4; ++rr) acc[rr] = make_float4(0.f, 0.f, 0.f, 0.f);

#define HSTEP(q0) do {                                                        \
    const float4 wa = *(const float4*)&wl[(q0)];                              \
    const float4 wb = *(const float4*)&wl[(q0) + 4];                          \
    _Pragma("unroll")                                                         \
    for (int rr = 0; rr < 4; ++rr) {                                          \
        const float4 v = *(const float4*)&sr[rr][(q0) - 4 + x0];              \
        acc[rr].x = fmaf(v.x, wa.w, acc[rr].x);                               \
        acc[rr].x = fmaf(v.y, wb.x, acc[rr].x);                               \
        acc[rr].x = fmaf(v.z, wb.y, acc[rr].x);                               \
        acc[rr].x = fmaf(v.w, wb.z, acc[rr].x);                               \
        acc[rr].y = fmaf(v.x, wa.z, acc[rr].y);                               \
        acc[rr].y = fmaf(v.y, wa.w, acc[rr].y);                               \
        acc[rr].y = fmaf(v.z, wb.x, acc[rr].y);                               \
        acc[rr].y = fmaf(v.w, wb.y, acc[rr].y);                               \
        acc[rr].z = fmaf(v.x, wa.y, acc[rr].z);                               \
        acc[rr].z = fmaf(v.y, wa.z, acc[rr].z);                               \
        acc[rr].z = fmaf(v.z, wa.w, acc[rr].z);                               \
        acc[rr].z = fmaf(v.w, wb.x, acc[rr].z);                               \
        acc[rr].w = fmaf(v.x, wa.x, acc[rr].w);                               \
        acc[rr].w = fmaf(v.y, wa.y, acc[rr].w);                               \
        acc[rr].w = fmaf(v.z, wa.z, acc[rr].w);                               \
        acc[rr].w = fmaf(v.w, wa.w, acc[rr].w);                               \
    }                                                                         \
} while (0)
    // q0 walks 64-rp .. 64+rp step 4; M steps (always odd): peel 1, unroll 2
    const int qend = 64 + rp;
    int q0 = 64 - rp;
    HSTEP(q0);
    q0 += 4;
    for (; q0 <= qend; q0 += 8) {
        HSTEP(q0);
        HSTEP(q0 + 4);
    }
#undef HSTEP
#pragma unroll
    for (int rr = 0; rr < 4; ++rr)
        *(float4*)(outp + (size_t)(ybase + rr) * NW + x0) = acc[rr];
}

// Vertical pass: one 16-row tile per WAVE (16 float4 accumulators in VGPRs),
// double-buffered 8-row chunk prefetch (va/vb, all statically indexed).
__global__ __launch_bounds__(256, 2) void vpass(const float* __restrict__ tmp,
                                                const float* __restrict__ wpadV,
                                                const int* __restrict__ steps,
                                                const float* __restrict__ sigmas,
                                                float* __restrict__ out) {
    __shared__ __align__(16) float wl[WPV];
    const int nwg = NPLANE * VPB;                      // 768
    const int pb = blockIdx.x;
    const int lbid = (pb & 7) * (nwg >> 3) + (pb >> 3);
    const int plane = lbid / VPB;
    const int b = plane / NC;
    const int t = threadIdx.x;
    if (t < WPV / 4) ((float4*)wl)[t] = ((const float4*)(wpadV + b * WPV))[t];
    __syncthreads();

    const float sg = sigmas[steps[b]];
    const int rp = ((int)ceilf(3.0f * sg) + 3) & ~3;
    const int NI = 2 + rp / 4;                         // 8-row chunks
    const int wave = t >> 6, lane = t & 63;
    const int tile = (lbid % VPB) * 4 + wave;          // 0..15
    const int yt = tile * 16;
    const int x0 = lane * 4;
    const float* __restrict__ plptr = tmp + (size_t)plane * NH * NW;
    float* __restrict__ outp = out + (size_t)plane * NH * NW;

    float4 acc[16];
#pragma unroll
    for (int j = 0; j < 16; ++j) acc[j] = make_float4(0.f, 0.f, 0.f, 0.f);

#define VLOAD(dst, itv) do {                                                  \
    const int i0_ = yt - rp + 8 * (itv);                                      \
    _Pragma("unroll")                                                         \
    for (int di = 0; di < 8; ++di)                                            \
        dst[di] = *(const float4*)(plptr + (size_t)refl(i0_ + di) * NW + x0); \
} while (0)

#define VFMA(src, itv) do {                                                   \
    const int s0_ = 72 - rp + 8 * (itv);                                      \
    float wv[24];                                                             \
    _Pragma("unroll")                                                         \
    for (int k = 0; k < 6; ++k)                                               \
        *(float4*)&wv[4 * k] = *(const float4*)&wl[s0_ - 12 + 4 * k];         \
    _Pragma("unroll")                                                         \
    for (int di = 0; di < 8; ++di) {                                          \
        const float4 v = src[di];                                             \
        _Pragma("unroll")                                                     \
        for (int j = 0; j < 16; ++j) {                                        \
            const float w = wv[16 + di - j];       /* tap (i0+di)-(yt+j) */   \
            acc[j].x = fmaf(v.x, w, acc[j].x);                                \
            acc[j].y = fmaf(v.y, w, acc[j].y);                                \
            acc[j].z = fmaf(v.z, w, acc[j].z);                                \
            acc[j].w = fmaf(v.w, w, acc[j].w);                                \
        }                                                                     \
    }                                                                         \
} while (0)

    float4 va[8], vb[8];
    VLOAD(va, 0);
    int it = 0;
    for (;;) {
        if (it + 1 < NI) VLOAD(vb, it + 1);    // prefetch under va's FMAs
        VFMA(va, it);
        ++it; if (it >= NI) break;
        if (it + 1 < NI) VLOAD(va, it + 1);    // prefetch under vb's FMAs
        VFMA(vb, it);
        ++it; if (it >= NI) break;
    }
#undef VLOAD
#undef VFMA

#pragma unroll
    for (int j = 0; j < 16; ++j)
        *(float4*)(outp + (size_t)(yt + j) * NW + x0) = acc[j];
}

extern "C" void kernel_launch(void* const* d_in, const int* in_sizes, int n_in,
                              void* d_out, int out_size, void* d_ws, size_t ws_size,
                              hipStream_t stream) {
    const float* x      = (const float*)d_in[0];
    const int*   steps  = (const int*)d_in[1];
    const float* sigmas = (const float*)d_in[2];
    float* out = (float*)d_out;
    const int B = in_sizes[1];              // 64

    float* wpadH = (float*)d_ws;                                    // B*WPH floats
    float* wpadV = wpadH + (size_t)B * WPH;                         // B*WPV floats
    float* tmp   = wpadV + (size_t)B * WPV;                         // B*C*H*W floats

    wgen<<<dim3(B), dim3(64), 0, stream>>>(steps, sigmas, wpadH, wpadV);
    hpass<<<dim3(NPLANE * HPB), dim3(256), 0, stream>>>(x, wpadH, steps, sigmas, tmp);
    vpass<<<dim3(NPLANE * VPB), dim3(256), 0, stream>>>(tmp, wpadV, steps, sigmas, out);
}